// Round 1
// baseline (165.283 us; speedup 1.0000x reference)
//
#include <hip/hip_runtime.h>

// Trilinear resampler, REPLICATE (clamp) boundary.
// inputs:  [B, D, H, W, C] fp32   (B=2, D=H=W=128, C=8)
// coords:  [B, GD, GH, GW, 3] fp32, order (d, h, w)
// output:  [B, GD, GH, GW, C] fp32

constexpr int B  = 2;
constexpr int D  = 128;
constexpr int H  = 128;
constexpr int W  = 128;
constexpr int C  = 8;
constexpr int GD = 96;
constexpr int GH = 96;
constexpr int GW = 96;
constexpr long long PTS_PER_B = (long long)GD * GH * GW;   // 884736
constexpr long long NPTS      = (long long)B * PTS_PER_B;  // 1769472

__global__ __launch_bounds__(256)
void resample_trilinear(const float* __restrict__ inp,
                        const float* __restrict__ coords,
                        float* __restrict__ out)
{
    long long i = (long long)blockIdx.x * blockDim.x + threadIdx.x;
    if (i >= NPTS) return;

    int b = (int)(i / PTS_PER_B);

    // coords for this point: 3 consecutive floats (d, h, w)
    const float zc = coords[3 * i + 0];
    const float yc = coords[3 * i + 1];
    const float xc = coords[3 * i + 2];

    const float fz = floorf(zc);
    const float fy = floorf(yc);
    const float fx = floorf(xc);

    float wz1 = zc - fz, wz0 = 1.0f - wz1;
    float wy1 = yc - fy, wy0 = 1.0f - wy1;
    float wx1 = xc - fx, wx0 = 1.0f - wx1;

    int z0 = (int)fz;  int y0 = (int)fy;  int x0 = (int)fx;
    // replicate boundary: clamp both corners into [0, size-1]
    z0 = min(max(z0, 0), D - 1);
    y0 = min(max(y0, 0), H - 1);
    x0 = min(max(x0, 0), W - 1);
    const int z1 = min(z0 + 1, D - 1);
    const int y1 = min(y0 + 1, H - 1);
    const int x1 = min(x0 + 1, W - 1);

    const long long bb = (long long)b * D;

    float4 acc_lo = make_float4(0.f, 0.f, 0.f, 0.f);
    float4 acc_hi = make_float4(0.f, 0.f, 0.f, 0.f);

    const int   zs[2] = {z0, z1};
    const int   ys[2] = {y0, y1};
    const int   xs[2] = {x0, x1};
    const float wzs[2] = {wz0, wz1};
    const float wys[2] = {wy0, wy1};
    const float wxs[2] = {wx0, wx1};

#pragma unroll
    for (int iz = 0; iz < 2; ++iz) {
#pragma unroll
        for (int iy = 0; iy < 2; ++iy) {
#pragma unroll
            for (int ix = 0; ix < 2; ++ix) {
                const float wt = wzs[iz] * wys[iy] * wxs[ix];
                const long long base =
                    ((((bb + zs[iz]) * H + ys[iy]) * W) + xs[ix]) * (long long)C;
                const float4 v0 = *reinterpret_cast<const float4*>(inp + base);
                const float4 v1 = *reinterpret_cast<const float4*>(inp + base + 4);
                acc_lo.x += wt * v0.x;  acc_lo.y += wt * v0.y;
                acc_lo.z += wt * v0.z;  acc_lo.w += wt * v0.w;
                acc_hi.x += wt * v1.x;  acc_hi.y += wt * v1.y;
                acc_hi.z += wt * v1.z;  acc_hi.w += wt * v1.w;
            }
        }
    }

    float* o = out + i * C;
    *reinterpret_cast<float4*>(o)     = acc_lo;
    *reinterpret_cast<float4*>(o + 4) = acc_hi;
}

extern "C" void kernel_launch(void* const* d_in, const int* in_sizes, int n_in,
                              void* d_out, int out_size, void* d_ws, size_t ws_size,
                              hipStream_t stream)
{
    const float* inp    = (const float*)d_in[0];
    const float* coords = (const float*)d_in[1];
    float* out          = (float*)d_out;

    const int threads = 256;
    const long long blocks = (NPTS + threads - 1) / threads;
    resample_trilinear<<<dim3((unsigned)blocks), dim3(threads), 0, stream>>>(inp, coords, out);
}